// Round 1
// baseline (477.122 us; speedup 1.0000x reference)
//
#include <hip/hip_runtime.h>

#define N_NODES 50000
#define D 128
#define E_EDGES 800000
#define EPS 1e-5f

// ---------------- Kernel 1: LayerNorm (no affine). One wave per row. ----------------
__global__ __launch_bounds__(256) void ln_kernel(const float* __restrict__ x,
                                                 float* __restrict__ ln) {
    int wave = threadIdx.x >> 6;
    int lane = threadIdx.x & 63;
    int row  = blockIdx.x * 4 + wave;
    if (row >= N_NODES) return;
    const float2* xr = (const float2*)(x + (size_t)row * D);
    float2 v = xr[lane];
    float s = v.x + v.y;
    #pragma unroll
    for (int off = 32; off > 0; off >>= 1) s += __shfl_xor(s, off);
    float mu = s * (1.0f / D);
    float dx = v.x - mu, dy = v.y - mu;
    float vs = dx * dx + dy * dy;
    #pragma unroll
    for (int off = 32; off > 0; off >>= 1) vs += __shfl_xor(vs, off);
    float rstd = rsqrtf(vs * (1.0f / D) + EPS);
    float2 o; o.x = dx * rstd; o.y = dy * rstd;
    ((float2*)(ln + (size_t)row * D))[lane] = o;
}

// ---------------- Kernel 2: H = LN @ W  (f32, VALU). 32 rows x 128 cols / block. ----
__global__ __launch_bounds__(256) void gemm_kernel(const float* __restrict__ A,
                                                   const float* __restrict__ W,
                                                   float* __restrict__ H) {
    __shared__ float As[32][128];    // 16 KB
    __shared__ float Ws[128][128];   // 64 KB
    int tid  = threadIdx.x;
    int row0 = blockIdx.x * 32;

    { // stage W (whole 128x128) into LDS
        const float4* Wv  = (const float4*)W;
        float4*       Wsv = (float4*)&Ws[0][0];
        #pragma unroll
        for (int i = 0; i < 16; ++i) Wsv[tid + 256 * i] = Wv[tid + 256 * i];
    }
    { // stage A tile
        int nrow = N_NODES - row0; if (nrow > 32) nrow = 32;
        const float4* Av  = (const float4*)(A + (size_t)row0 * D);
        float4*       Asv = (float4*)&As[0][0];
        int n4 = nrow * 32;
        for (int i = tid; i < n4; i += 256) Asv[i] = Av[i];
    }
    __syncthreads();

    int tx = tid & 31, ty = tid >> 5;
    int c0 = tx * 4;
    int r0 = ty * 4;
    float4 acc[4] = {};
    #pragma unroll 4
    for (int k = 0; k < 128; ++k) {
        float4 w = *(const float4*)&Ws[k][c0];
        float a[4];
        #pragma unroll
        for (int j = 0; j < 4; ++j) a[j] = As[r0 + j][k];
        #pragma unroll
        for (int j = 0; j < 4; ++j) {
            acc[j].x = fmaf(a[j], w.x, acc[j].x);
            acc[j].y = fmaf(a[j], w.y, acc[j].y);
            acc[j].z = fmaf(a[j], w.z, acc[j].z);
            acc[j].w = fmaf(a[j], w.w, acc[j].w);
        }
    }
    #pragma unroll
    for (int j = 0; j < 4; ++j) {
        int row = row0 + r0 + j;
        if (row < N_NODES)
            *(float4*)(H + (size_t)row * D + c0) = acc[j];
    }
}

// ---------------- Kernel 3: out[n][d] = b[d] ----------------
__global__ __launch_bounds__(256) void init_out(const float* __restrict__ b,
                                                float4* __restrict__ out4) {
    int i = blockIdx.x * 256 + threadIdx.x;   // 1.6M float4s
    out4[i] = ((const float4*)b)[i & 31];
}

// ---------------- Kernel 4: scatter-add msgs. 32 threads per edge. ----------------
__global__ __launch_bounds__(256) void scatter_kernel(const int* __restrict__ ei,
                                                      const float* __restrict__ ew,
                                                      const float* __restrict__ H,
                                                      float* __restrict__ out) {
    int t = blockIdx.x * 256 + threadIdx.x;   // E*32 = 25.6M < 2^31
    int e = t >> 5, q = t & 31;
    int src = ei[e];
    int dst = ei[E_EDGES + e];
    float w = ew[e];
    const float* hs = H + (size_t)src * D;
    float*       od = out + (size_t)dst * D;
    #pragma unroll
    for (int j = 0; j < 4; ++j) {
        int c = j * 32 + q;                   // wave's lanes cover contiguous dwords
        atomicAdd(&od[c], w * hs[c]);
    }
}

// ---------------- Kernel 5: out = out * mask - ln ----------------
__global__ __launch_bounds__(256) void finalize(const float* __restrict__ mask,
                                                const float* __restrict__ ln,
                                                float* __restrict__ out) {
    int i = blockIdx.x * 256 + threadIdx.x;   // 1.6M float4s
    float4 a = ((float4*)out)[i];
    float4 m = ((const float4*)mask)[i];
    float4 l = ((const float4*)ln)[i];
    float4 r;
    r.x = a.x * m.x - l.x;
    r.y = a.y * m.y - l.y;
    r.z = a.z * m.z - l.z;
    r.w = a.w * m.w - l.w;
    ((float4*)out)[i] = r;
}

extern "C" void kernel_launch(void* const* d_in, const int* in_sizes, int n_in,
                              void* d_out, int out_size, void* d_ws, size_t ws_size,
                              hipStream_t stream) {
    const float* node_inputs = (const float*)d_in[0];
    const int*   edge_index  = (const int*)d_in[1];
    const float* edge_w      = (const float*)d_in[2];
    const float* W           = (const float*)d_in[3];
    const float* b           = (const float*)d_in[4];
    const float* mask        = (const float*)d_in[5];
    float* out = (float*)d_out;

    float* ln = (float*)d_ws;                       // N*D f32 = 25.6 MB
    float* h  = ln + (size_t)N_NODES * D;           // N*D f32 = 25.6 MB

    ln_kernel<<<N_NODES / 4, 256, 0, stream>>>(node_inputs, ln);
    gemm_kernel<<<(N_NODES + 31) / 32, 256, 0, stream>>>(ln, W, h);
    init_out<<<(N_NODES * D / 4) / 256, 256, 0, stream>>>(b, (float4*)out);
    scatter_kernel<<<(E_EDGES * 32) / 256, 256, 0, stream>>>(edge_index, edge_w, h, out);
    finalize<<<(N_NODES * D / 4) / 256, 256, 0, stream>>>(mask, ln, out);
}

// Round 2
// 404.283 us; speedup vs baseline: 1.1802x; 1.1802x over previous
//
#include <hip/hip_runtime.h>

#define N_NODES 50000
#define D 128
#define E_EDGES 800000
#define EPS 1e-5f

// ---------------- Kernel 1: LayerNorm (no affine). One wave per row. ----------------
__global__ __launch_bounds__(256) void ln_kernel(const float* __restrict__ x,
                                                 float* __restrict__ ln) {
    int wave = threadIdx.x >> 6;
    int lane = threadIdx.x & 63;
    int row  = blockIdx.x * 4 + wave;
    if (row >= N_NODES) return;
    const float2* xr = (const float2*)(x + (size_t)row * D);
    float2 v = xr[lane];
    float s = v.x + v.y;
    #pragma unroll
    for (int off = 32; off > 0; off >>= 1) s += __shfl_xor(s, off);
    float mu = s * (1.0f / D);
    float dx = v.x - mu, dy = v.y - mu;
    float vs = dx * dx + dy * dy;
    #pragma unroll
    for (int off = 32; off > 0; off >>= 1) vs += __shfl_xor(vs, off);
    float rstd = rsqrtf(vs * (1.0f / D) + EPS);
    float2 o; o.x = dx * rstd; o.y = dy * rstd;
    ((float2*)(ln + (size_t)row * D))[lane] = o;
}

// ---------------- Kernel 2: H = LN @ W  (f32, VALU). 32 rows x 128 cols / block. ----
__global__ __launch_bounds__(256) void gemm_kernel(const float* __restrict__ A,
                                                   const float* __restrict__ W,
                                                   float* __restrict__ H) {
    __shared__ float As[32][128];    // 16 KB
    __shared__ float Ws[128][128];   // 64 KB
    int tid  = threadIdx.x;
    int row0 = blockIdx.x * 32;

    { // stage W (whole 128x128) into LDS
        const float4* Wv  = (const float4*)W;
        float4*       Wsv = (float4*)&Ws[0][0];
        #pragma unroll
        for (int i = 0; i < 16; ++i) Wsv[tid + 256 * i] = Wv[tid + 256 * i];
    }
    { // stage A tile
        int nrow = N_NODES - row0; if (nrow > 32) nrow = 32;
        const float4* Av  = (const float4*)(A + (size_t)row0 * D);
        float4*       Asv = (float4*)&As[0][0];
        int n4 = nrow * 32;
        for (int i = tid; i < n4; i += 256) Asv[i] = Av[i];
    }
    __syncthreads();

    int tx = tid & 31, ty = tid >> 5;
    int c0 = tx * 4;
    int r0 = ty * 4;
    float4 acc[4] = {};
    #pragma unroll 4
    for (int k = 0; k < 128; ++k) {
        float4 w = *(const float4*)&Ws[k][c0];
        float a[4];
        #pragma unroll
        for (int j = 0; j < 4; ++j) a[j] = As[r0 + j][k];
        #pragma unroll
        for (int j = 0; j < 4; ++j) {
            acc[j].x = fmaf(a[j], w.x, acc[j].x);
            acc[j].y = fmaf(a[j], w.y, acc[j].y);
            acc[j].z = fmaf(a[j], w.z, acc[j].z);
            acc[j].w = fmaf(a[j], w.w, acc[j].w);
        }
    }
    #pragma unroll
    for (int j = 0; j < 4; ++j) {
        int row = row0 + r0 + j;
        if (row < N_NODES)
            *(float4*)(H + (size_t)row * D + c0) = acc[j];
    }
}

// ---------------- Kernel 3: zero the degree histogram ----------------
__global__ __launch_bounds__(256) void zero_counts(int* __restrict__ counts) {
    int i = blockIdx.x * 256 + threadIdx.x;
    if (i < N_NODES) counts[i] = 0;
}

// ---------------- Kernel 4: histogram of dst ----------------
__global__ __launch_bounds__(256) void hist_kernel(const int* __restrict__ ei,
                                                   int* __restrict__ counts) {
    int e = blockIdx.x * 256 + threadIdx.x;
    if (e < E_EDGES) atomicAdd(&counts[ei[E_EDGES + e]], 1);
}

// ---------------- Kernel 5: single-block scan -> row_start, cursor ----------------
#define SCAN_T 1024
__global__ __launch_bounds__(SCAN_T) void scan_kernel(const int* __restrict__ counts,
                                                      int* __restrict__ row_start,
                                                      int* __restrict__ cursor) {
    __shared__ int ssum[SCAN_T];
    int t = threadIdx.x;
    const int ITEMS = (N_NODES + SCAN_T - 1) / SCAN_T;   // 49
    int i0 = t * ITEMS;
    int i1 = i0 + ITEMS; if (i1 > N_NODES) i1 = N_NODES;
    int local = 0;
    for (int i = i0; i < i1; ++i) local += counts[i];
    ssum[t] = local;
    __syncthreads();
    // Hillis-Steele inclusive scan over thread sums
    for (int off = 1; off < SCAN_T; off <<= 1) {
        int v = ssum[t];
        int u = (t >= off) ? ssum[t - off] : 0;
        __syncthreads();
        ssum[t] = v + u;
        __syncthreads();
    }
    int run = (t == 0) ? 0 : ssum[t - 1];                // exclusive prefix
    for (int i = i0; i < i1; ++i) {
        row_start[i] = run;
        cursor[i]    = run;
        run += counts[i];
    }
    if (t == SCAN_T - 1) row_start[N_NODES] = E_EDGES;
}

// ---------------- Kernel 6: reorder edges into CSR order ----------------
__global__ __launch_bounds__(256) void reorder_kernel(const int* __restrict__ ei,
                                                      const float* __restrict__ ew,
                                                      int* __restrict__ cursor,
                                                      int* __restrict__ src_s,
                                                      float* __restrict__ w_s) {
    int e = blockIdx.x * 256 + threadIdx.x;
    if (e >= E_EDGES) return;
    int dst = ei[E_EDGES + e];
    int pos = atomicAdd(&cursor[dst], 1);
    src_s[pos] = ei[e];
    w_s[pos]   = ew[e];
}

// ------- Kernel 7: gather-aggregate + fused bias/dropout/residual epilogue -------
// One wave per node; lane covers 2 of D=128 floats.
__global__ __launch_bounds__(256) void gather_kernel(const int* __restrict__ row_start,
                                                     const int* __restrict__ src_s,
                                                     const float* __restrict__ w_s,
                                                     const float* __restrict__ H,
                                                     const float* __restrict__ b,
                                                     const float* __restrict__ mask,
                                                     const float* __restrict__ ln,
                                                     float* __restrict__ out) {
    int wave = threadIdx.x >> 6;
    int lane = threadIdx.x & 63;
    int node = blockIdx.x * 4 + wave;
    if (node >= N_NODES) return;
    int beg = row_start[node], end = row_start[node + 1];
    float2 acc = make_float2(0.f, 0.f);
    int e = beg;
    for (; e + 2 <= end; e += 2) {                       // 2-edge ILP
        int   s0 = src_s[e],   s1 = src_s[e + 1];
        float w0 = w_s[e],     w1 = w_s[e + 1];
        float2 h0 = *(const float2*)(H + (size_t)s0 * D + lane * 2);
        float2 h1 = *(const float2*)(H + (size_t)s1 * D + lane * 2);
        acc.x = fmaf(w0, h0.x, acc.x); acc.y = fmaf(w0, h0.y, acc.y);
        acc.x = fmaf(w1, h1.x, acc.x); acc.y = fmaf(w1, h1.y, acc.y);
    }
    if (e < end) {
        int s0 = src_s[e]; float w0 = w_s[e];
        float2 h0 = *(const float2*)(H + (size_t)s0 * D + lane * 2);
        acc.x = fmaf(w0, h0.x, acc.x); acc.y = fmaf(w0, h0.y, acc.y);
    }
    size_t o = (size_t)node * D + lane * 2;
    float2 bv = *(const float2*)(b + lane * 2);
    float2 mv = *(const float2*)(mask + o);
    float2 lv = *(const float2*)(ln + o);
    float2 r;
    r.x = (acc.x + bv.x) * mv.x - lv.x;
    r.y = (acc.y + bv.y) * mv.y - lv.y;
    *(float2*)(out + o) = r;
}

extern "C" void kernel_launch(void* const* d_in, const int* in_sizes, int n_in,
                              void* d_out, int out_size, void* d_ws, size_t ws_size,
                              hipStream_t stream) {
    const float* node_inputs = (const float*)d_in[0];
    const int*   edge_index  = (const int*)d_in[1];
    const float* edge_w      = (const float*)d_in[2];
    const float* W           = (const float*)d_in[3];
    const float* b           = (const float*)d_in[4];
    const float* mask        = (const float*)d_in[5];
    float* out = (float*)d_out;

    const size_t ND = (size_t)N_NODES * D;
    const int NP = 50004;                       // padded N+1, keeps 16B alignment
    float* ln        = (float*)d_ws;            // ND f32
    float* h         = ln + ND;                 // ND f32
    int*   row_start = (int*)(h + ND);          // NP ints
    int*   cursor    = row_start + NP;          // NP ints
    int*   counts    = cursor + NP;             // NP ints
    int*   src_s     = counts + NP;             // E ints
    float* w_s       = (float*)(src_s + E_EDGES); // E f32

    ln_kernel<<<N_NODES / 4, 256, 0, stream>>>(node_inputs, ln);
    gemm_kernel<<<(N_NODES + 31) / 32, 256, 0, stream>>>(ln, W, h);
    zero_counts<<<(N_NODES + 255) / 256, 256, 0, stream>>>(counts);
    hist_kernel<<<(E_EDGES + 255) / 256, 256, 0, stream>>>(edge_index, counts);
    scan_kernel<<<1, SCAN_T, 0, stream>>>(counts, row_start, cursor);
    reorder_kernel<<<(E_EDGES + 255) / 256, 256, 0, stream>>>(edge_index, edge_w,
                                                              cursor, src_s, w_s);
    gather_kernel<<<(N_NODES + 3) / 4, 256, 0, stream>>>(row_start, src_s, w_s, h,
                                                         b, mask, ln, out);
}

// Round 3
// 308.268 us; speedup vs baseline: 1.5477x; 1.3115x over previous
//
#include <hip/hip_runtime.h>

#define N_NODES 50000
#define D 128
#define E_EDGES 800000
#define EPS 1e-5f
#define NB 196   // ceil(N_NODES/256)

// ---------------- Kernel 1: LayerNorm (no affine). One wave per row. ----------------
__global__ __launch_bounds__(256) void ln_kernel(const float* __restrict__ x,
                                                 float* __restrict__ ln) {
    int wave = threadIdx.x >> 6;
    int lane = threadIdx.x & 63;
    int row  = blockIdx.x * 4 + wave;
    if (row >= N_NODES) return;
    const float2* xr = (const float2*)(x + (size_t)row * D);
    float2 v = xr[lane];
    float s = v.x + v.y;
    #pragma unroll
    for (int off = 32; off > 0; off >>= 1) s += __shfl_xor(s, off);
    float mu = s * (1.0f / D);
    float dx = v.x - mu, dy = v.y - mu;
    float vs = dx * dx + dy * dy;
    #pragma unroll
    for (int off = 32; off > 0; off >>= 1) vs += __shfl_xor(vs, off);
    float rstd = rsqrtf(vs * (1.0f / D) + EPS);
    float2 o; o.x = dx * rstd; o.y = dy * rstd;
    ((float2*)(ln + (size_t)row * D))[lane] = o;
}

// ---------------- Kernel 2: H = LN @ W  (f32, VALU). 32 rows x 128 cols / block. ----
__global__ __launch_bounds__(256) void gemm_kernel(const float* __restrict__ A,
                                                   const float* __restrict__ W,
                                                   float* __restrict__ H) {
    __shared__ float As[32][128];    // 16 KB
    __shared__ float Ws[128][128];   // 64 KB
    int tid  = threadIdx.x;
    int row0 = blockIdx.x * 32;

    { // stage W (whole 128x128) into LDS
        const float4* Wv  = (const float4*)W;
        float4*       Wsv = (float4*)&Ws[0][0];
        #pragma unroll
        for (int i = 0; i < 16; ++i) Wsv[tid + 256 * i] = Wv[tid + 256 * i];
    }
    { // stage A tile
        int nrow = N_NODES - row0; if (nrow > 32) nrow = 32;
        const float4* Av  = (const float4*)(A + (size_t)row0 * D);
        float4*       Asv = (float4*)&As[0][0];
        int n4 = nrow * 32;
        for (int i = tid; i < n4; i += 256) Asv[i] = Av[i];
    }
    __syncthreads();

    int tx = tid & 31, ty = tid >> 5;
    int c0 = tx * 4;
    int r0 = ty * 4;
    float4 acc[4] = {};
    #pragma unroll 4
    for (int k = 0; k < 128; ++k) {
        float4 w = *(const float4*)&Ws[k][c0];
        float a[4];
        #pragma unroll
        for (int j = 0; j < 4; ++j) a[j] = As[r0 + j][k];
        #pragma unroll
        for (int j = 0; j < 4; ++j) {
            acc[j].x = fmaf(a[j], w.x, acc[j].x);
            acc[j].y = fmaf(a[j], w.y, acc[j].y);
            acc[j].z = fmaf(a[j], w.z, acc[j].z);
            acc[j].w = fmaf(a[j], w.w, acc[j].w);
        }
    }
    #pragma unroll
    for (int j = 0; j < 4; ++j) {
        int row = row0 + r0 + j;
        if (row < N_NODES)
            *(float4*)(H + (size_t)row * D + c0) = acc[j];
    }
}

// ---------------- Kernel 3: zero the degree histogram ----------------
__global__ __launch_bounds__(256) void zero_counts(int* __restrict__ counts) {
    int i = blockIdx.x * 256 + threadIdx.x;
    if (i < N_NODES) counts[i] = 0;
}

// ---------------- Kernel 4: histogram of dst ----------------
__global__ __launch_bounds__(256) void hist_kernel(const int* __restrict__ ei,
                                                   int* __restrict__ counts) {
    int e = blockIdx.x * 256 + threadIdx.x;
    if (e < E_EDGES) atomicAdd(&counts[ei[E_EDGES + e]], 1);
}

// ---------------- Kernel 5a: per-block sums of counts ----------------
__global__ __launch_bounds__(256) void blocksum_kernel(const int* __restrict__ counts,
                                                       int* __restrict__ partial) {
    __shared__ int red[256];
    int i = blockIdx.x * 256 + threadIdx.x;
    red[threadIdx.x] = (i < N_NODES) ? counts[i] : 0;
    __syncthreads();
    #pragma unroll
    for (int off = 128; off > 0; off >>= 1) {
        if (threadIdx.x < off) red[threadIdx.x] += red[threadIdx.x + off];
        __syncthreads();
    }
    if (threadIdx.x == 0) partial[blockIdx.x] = red[0];
}

// ---------------- Kernel 5b: exclusive scan of the 196 partials (1 block) --------
__global__ __launch_bounds__(256) void scanpartial_kernel(int* __restrict__ partial) {
    __shared__ int s[256];
    int t = threadIdx.x;
    s[t] = (t < NB) ? partial[t] : 0;
    __syncthreads();
    #pragma unroll
    for (int off = 1; off < 256; off <<= 1) {
        int u = (t >= off) ? s[t - off] : 0;
        __syncthreads();
        s[t] += u;
        __syncthreads();
    }
    if (t < NB) partial[t] = (t == 0) ? 0 : s[t - 1];
}

// ---------------- Kernel 5c: block-local scan + partial offset -> row_start ------
__global__ __launch_bounds__(256) void writeoffs_kernel(const int* __restrict__ counts,
                                                        const int* __restrict__ partial,
                                                        int* __restrict__ row_start,
                                                        int* __restrict__ cursor) {
    __shared__ int s[256];
    int t = threadIdx.x;
    int i = blockIdx.x * 256 + t;
    s[t] = (i < N_NODES) ? counts[i] : 0;
    __syncthreads();
    #pragma unroll
    for (int off = 1; off < 256; off <<= 1) {
        int u = (t >= off) ? s[t - off] : 0;
        __syncthreads();
        s[t] += u;
        __syncthreads();
    }
    int excl = partial[blockIdx.x] + ((t == 0) ? 0 : s[t - 1]);
    if (i < N_NODES) { row_start[i] = excl; cursor[i] = excl; }
    if (i == N_NODES - 1) row_start[N_NODES] = E_EDGES;
}

// ---------------- Kernel 6: reorder edges into CSR order ----------------
__global__ __launch_bounds__(256) void reorder_kernel(const int* __restrict__ ei,
                                                      const float* __restrict__ ew,
                                                      int* __restrict__ cursor,
                                                      int* __restrict__ src_s,
                                                      float* __restrict__ w_s) {
    int e = blockIdx.x * 256 + threadIdx.x;
    if (e >= E_EDGES) return;
    int dst = ei[E_EDGES + e];
    int pos = atomicAdd(&cursor[dst], 1);
    src_s[pos] = ei[e];
    w_s[pos]   = ew[e];
}

// ------- Kernel 7: gather-aggregate + fused bias/dropout/residual epilogue -------
// One wave per node; lane covers 2 of D=128 floats.
__global__ __launch_bounds__(256) void gather_kernel(const int* __restrict__ row_start,
                                                     const int* __restrict__ src_s,
                                                     const float* __restrict__ w_s,
                                                     const float* __restrict__ H,
                                                     const float* __restrict__ b,
                                                     const float* __restrict__ mask,
                                                     const float* __restrict__ ln,
                                                     float* __restrict__ out) {
    int wave = threadIdx.x >> 6;
    int lane = threadIdx.x & 63;
    int node = blockIdx.x * 4 + wave;
    if (node >= N_NODES) return;
    int beg = row_start[node], end = row_start[node + 1];
    float2 acc = make_float2(0.f, 0.f);
    int e = beg;
    for (; e + 2 <= end; e += 2) {                       // 2-edge ILP
        int   s0 = src_s[e],   s1 = src_s[e + 1];
        float w0 = w_s[e],     w1 = w_s[e + 1];
        float2 h0 = *(const float2*)(H + (size_t)s0 * D + lane * 2);
        float2 h1 = *(const float2*)(H + (size_t)s1 * D + lane * 2);
        acc.x = fmaf(w0, h0.x, acc.x); acc.y = fmaf(w0, h0.y, acc.y);
        acc.x = fmaf(w1, h1.x, acc.x); acc.y = fmaf(w1, h1.y, acc.y);
    }
    if (e < end) {
        int s0 = src_s[e]; float w0 = w_s[e];
        float2 h0 = *(const float2*)(H + (size_t)s0 * D + lane * 2);
        acc.x = fmaf(w0, h0.x, acc.x); acc.y = fmaf(w0, h0.y, acc.y);
    }
    size_t o = (size_t)node * D + lane * 2;
    float2 bv = *(const float2*)(b + lane * 2);
    float2 mv = *(const float2*)(mask + o);
    float2 lv = *(const float2*)(ln + o);
    float2 r;
    r.x = (acc.x + bv.x) * mv.x - lv.x;
    r.y = (acc.y + bv.y) * mv.y - lv.y;
    *(float2*)(out + o) = r;
}

extern "C" void kernel_launch(void* const* d_in, const int* in_sizes, int n_in,
                              void* d_out, int out_size, void* d_ws, size_t ws_size,
                              hipStream_t stream) {
    const float* node_inputs = (const float*)d_in[0];
    const int*   edge_index  = (const int*)d_in[1];
    const float* edge_w      = (const float*)d_in[2];
    const float* W           = (const float*)d_in[3];
    const float* b           = (const float*)d_in[4];
    const float* mask        = (const float*)d_in[5];
    float* out = (float*)d_out;

    const size_t ND = (size_t)N_NODES * D;
    const int NP = 50004;                       // padded N+1, keeps 16B alignment
    float* ln        = (float*)d_ws;            // ND f32
    float* h         = ln + ND;                 // ND f32
    int*   row_start = (int*)(h + ND);          // NP ints
    int*   cursor    = row_start + NP;          // NP ints
    int*   counts    = cursor + NP;             // NP ints
    int*   src_s     = counts + NP;             // E ints
    float* w_s       = (float*)(src_s + E_EDGES); // E f32
    int*   partial   = (int*)(w_s + E_EDGES);   // NB ints

    ln_kernel<<<N_NODES / 4, 256, 0, stream>>>(node_inputs, ln);
    gemm_kernel<<<(N_NODES + 31) / 32, 256, 0, stream>>>(ln, W, h);
    zero_counts<<<NB, 256, 0, stream>>>(counts);
    hist_kernel<<<(E_EDGES + 255) / 256, 256, 0, stream>>>(edge_index, counts);
    blocksum_kernel<<<NB, 256, 0, stream>>>(counts, partial);
    scanpartial_kernel<<<1, 256, 0, stream>>>(partial);
    writeoffs_kernel<<<NB, 256, 0, stream>>>(counts, partial, row_start, cursor);
    reorder_kernel<<<(E_EDGES + 255) / 256, 256, 0, stream>>>(edge_index, edge_w,
                                                              cursor, src_s, w_s);
    gather_kernel<<<(N_NODES + 3) / 4, 256, 0, stream>>>(row_start, src_s, w_s, h,
                                                         b, mask, ln, out);
}

// Round 4
// 290.591 us; speedup vs baseline: 1.6419x; 1.0608x over previous
//
#include <hip/hip_runtime.h>

#define N_NODES 50000
#define D 128
#define E_EDGES 800000
#define EPS 1e-5f
#define NB 196   // ceil(N_NODES/256)

// ---------------- Kernel 1: LayerNorm (no affine). One wave per row. ----------------
__global__ __launch_bounds__(256) void ln_kernel(const float* __restrict__ x,
                                                 float* __restrict__ ln) {
    int wave = threadIdx.x >> 6;
    int lane = threadIdx.x & 63;
    int row  = blockIdx.x * 4 + wave;
    if (row >= N_NODES) return;
    const float2* xr = (const float2*)(x + (size_t)row * D);
    float2 v = xr[lane];
    float s = v.x + v.y;
    #pragma unroll
    for (int off = 32; off > 0; off >>= 1) s += __shfl_xor(s, off);
    float mu = s * (1.0f / D);
    float dx = v.x - mu, dy = v.y - mu;
    float vs = dx * dx + dy * dy;
    #pragma unroll
    for (int off = 32; off > 0; off >>= 1) vs += __shfl_xor(vs, off);
    float rstd = rsqrtf(vs * (1.0f / D) + EPS);
    float2 o; o.x = dx * rstd; o.y = dy * rstd;
    ((float2*)(ln + (size_t)row * D))[lane] = o;
}

// ---------------- Kernel 2: H = LN @ W  (f32, VALU). 32 rows x 128 cols / block. ----
__global__ __launch_bounds__(256) void gemm_kernel(const float* __restrict__ A,
                                                   const float* __restrict__ W,
                                                   float* __restrict__ H) {
    __shared__ float As[32][128];    // 16 KB
    __shared__ float Ws[128][128];   // 64 KB
    int tid  = threadIdx.x;
    int row0 = blockIdx.x * 32;

    { // stage W (whole 128x128) into LDS
        const float4* Wv  = (const float4*)W;
        float4*       Wsv = (float4*)&Ws[0][0];
        #pragma unroll
        for (int i = 0; i < 16; ++i) Wsv[tid + 256 * i] = Wv[tid + 256 * i];
    }
    { // stage A tile
        int nrow = N_NODES - row0; if (nrow > 32) nrow = 32;
        const float4* Av  = (const float4*)(A + (size_t)row0 * D);
        float4*       Asv = (float4*)&As[0][0];
        int n4 = nrow * 32;
        for (int i = tid; i < n4; i += 256) Asv[i] = Av[i];
    }
    __syncthreads();

    int tx = tid & 31, ty = tid >> 5;
    int c0 = tx * 4;
    int r0 = ty * 4;
    float4 acc[4] = {};
    #pragma unroll 4
    for (int k = 0; k < 128; ++k) {
        float4 w = *(const float4*)&Ws[k][c0];
        float a[4];
        #pragma unroll
        for (int j = 0; j < 4; ++j) a[j] = As[r0 + j][k];
        #pragma unroll
        for (int j = 0; j < 4; ++j) {
            acc[j].x = fmaf(a[j], w.x, acc[j].x);
            acc[j].y = fmaf(a[j], w.y, acc[j].y);
            acc[j].z = fmaf(a[j], w.z, acc[j].z);
            acc[j].w = fmaf(a[j], w.w, acc[j].w);
        }
    }
    #pragma unroll
    for (int j = 0; j < 4; ++j) {
        int row = row0 + r0 + j;
        if (row < N_NODES)
            *(float4*)(H + (size_t)row * D + c0) = acc[j];
    }
}

// ---------------- Kernel 3: zero the degree histogram ----------------
__global__ __launch_bounds__(256) void zero_counts(int* __restrict__ counts) {
    int i = blockIdx.x * 256 + threadIdx.x;
    if (i < N_NODES) counts[i] = 0;
}

// ---------------- Kernel 4: histogram of dst ----------------
__global__ __launch_bounds__(256) void hist_kernel(const int* __restrict__ ei,
                                                   int* __restrict__ counts) {
    int e = blockIdx.x * 256 + threadIdx.x;
    if (e < E_EDGES) atomicAdd(&counts[ei[E_EDGES + e]], 1);
}

// ---------------- Kernel 5a: per-block sums of counts ----------------
__global__ __launch_bounds__(256) void blocksum_kernel(const int* __restrict__ counts,
                                                       int* __restrict__ partial) {
    __shared__ int red[256];
    int i = blockIdx.x * 256 + threadIdx.x;
    red[threadIdx.x] = (i < N_NODES) ? counts[i] : 0;
    __syncthreads();
    #pragma unroll
    for (int off = 128; off > 0; off >>= 1) {
        if (threadIdx.x < off) red[threadIdx.x] += red[threadIdx.x + off];
        __syncthreads();
    }
    if (threadIdx.x == 0) partial[blockIdx.x] = red[0];
}

// ---------------- Kernel 5b: exclusive scan of the 196 partials (1 block) --------
__global__ __launch_bounds__(256) void scanpartial_kernel(int* __restrict__ partial) {
    __shared__ int s[256];
    int t = threadIdx.x;
    s[t] = (t < NB) ? partial[t] : 0;
    __syncthreads();
    #pragma unroll
    for (int off = 1; off < 256; off <<= 1) {
        int u = (t >= off) ? s[t - off] : 0;
        __syncthreads();
        s[t] += u;
        __syncthreads();
    }
    if (t < NB) partial[t] = (t == 0) ? 0 : s[t - 1];
}

// ---------------- Kernel 5c: block-local scan + partial offset -> row_start ------
__global__ __launch_bounds__(256) void writeoffs_kernel(const int* __restrict__ counts,
                                                        const int* __restrict__ partial,
                                                        int* __restrict__ row_start,
                                                        int* __restrict__ cursor) {
    __shared__ int s[256];
    int t = threadIdx.x;
    int i = blockIdx.x * 256 + t;
    s[t] = (i < N_NODES) ? counts[i] : 0;
    __syncthreads();
    #pragma unroll
    for (int off = 1; off < 256; off <<= 1) {
        int u = (t >= off) ? s[t - off] : 0;
        __syncthreads();
        s[t] += u;
        __syncthreads();
    }
    int excl = partial[blockIdx.x] + ((t == 0) ? 0 : s[t - 1]);
    if (i < N_NODES) { row_start[i] = excl; cursor[i] = excl; }
    if (i == N_NODES - 1) row_start[N_NODES] = E_EDGES;
}

// ------- Kernel 6: reorder edges into CSR order, packed (src, w) int2 ------------
__global__ __launch_bounds__(256) void reorder_kernel(const int* __restrict__ ei,
                                                      const float* __restrict__ ew,
                                                      int* __restrict__ cursor,
                                                      int2* __restrict__ sw) {
    int e = blockIdx.x * 256 + threadIdx.x;
    if (e >= E_EDGES) return;
    int dst = ei[E_EDGES + e];
    int pos = atomicAdd(&cursor[dst], 1);
    int2 p; p.x = ei[e]; p.y = __float_as_int(ew[e]);
    sw[pos] = p;
}

// ------- Kernel 7: gather-aggregate + fused bias/dropout/residual epilogue -------
// Half-wave (32 lanes) per node; lane covers 4 of D=128 floats (float4).
__global__ __launch_bounds__(256) void gather_kernel(const int* __restrict__ row_start,
                                                     const int2* __restrict__ sw,
                                                     const float* __restrict__ H,
                                                     const float* __restrict__ b,
                                                     const float* __restrict__ mask,
                                                     const float* __restrict__ ln,
                                                     float* __restrict__ out) {
    int wave = threadIdx.x >> 6;
    int lane = threadIdx.x & 63;
    int half = lane >> 5;
    int l    = lane & 31;
    int node = blockIdx.x * 8 + wave * 2 + half;   // 6250 blocks * 8 = 50000 exact
    int beg = row_start[node], end = row_start[node + 1];
    const float4* H4 = (const float4*)H;
    float4 acc = make_float4(0.f, 0.f, 0.f, 0.f);
    int e = beg;
    for (; e + 4 <= end; e += 4) {                 // 4-edge MLP
        int2 p0 = sw[e], p1 = sw[e + 1], p2 = sw[e + 2], p3 = sw[e + 3];
        float4 h0 = H4[(size_t)p0.x * 32 + l];
        float4 h1 = H4[(size_t)p1.x * 32 + l];
        float4 h2 = H4[(size_t)p2.x * 32 + l];
        float4 h3 = H4[(size_t)p3.x * 32 + l];
        float w0 = __int_as_float(p0.y), w1 = __int_as_float(p1.y);
        float w2 = __int_as_float(p2.y), w3 = __int_as_float(p3.y);
        acc.x = fmaf(w0, h0.x, acc.x); acc.y = fmaf(w0, h0.y, acc.y);
        acc.z = fmaf(w0, h0.z, acc.z); acc.w = fmaf(w0, h0.w, acc.w);
        acc.x = fmaf(w1, h1.x, acc.x); acc.y = fmaf(w1, h1.y, acc.y);
        acc.z = fmaf(w1, h1.z, acc.z); acc.w = fmaf(w1, h1.w, acc.w);
        acc.x = fmaf(w2, h2.x, acc.x); acc.y = fmaf(w2, h2.y, acc.y);
        acc.z = fmaf(w2, h2.z, acc.z); acc.w = fmaf(w2, h2.w, acc.w);
        acc.x = fmaf(w3, h3.x, acc.x); acc.y = fmaf(w3, h3.y, acc.y);
        acc.z = fmaf(w3, h3.z, acc.z); acc.w = fmaf(w3, h3.w, acc.w);
    }
    for (; e < end; ++e) {
        int2 p0 = sw[e];
        float4 h0 = H4[(size_t)p0.x * 32 + l];
        float w0 = __int_as_float(p0.y);
        acc.x = fmaf(w0, h0.x, acc.x); acc.y = fmaf(w0, h0.y, acc.y);
        acc.z = fmaf(w0, h0.z, acc.z); acc.w = fmaf(w0, h0.w, acc.w);
    }
    size_t o4 = (size_t)node * 32 + l;
    float4 bv = ((const float4*)b)[l];
    float4 mv = ((const float4*)mask)[o4];
    float4 lv = ((const float4*)ln)[o4];
    float4 r;
    r.x = (acc.x + bv.x) * mv.x - lv.x;
    r.y = (acc.y + bv.y) * mv.y - lv.y;
    r.z = (acc.z + bv.z) * mv.z - lv.z;
    r.w = (acc.w + bv.w) * mv.w - lv.w;
    ((float4*)out)[o4] = r;
}

extern "C" void kernel_launch(void* const* d_in, const int* in_sizes, int n_in,
                              void* d_out, int out_size, void* d_ws, size_t ws_size,
                              hipStream_t stream) {
    const float* node_inputs = (const float*)d_in[0];
    const int*   edge_index  = (const int*)d_in[1];
    const float* edge_w      = (const float*)d_in[2];
    const float* W           = (const float*)d_in[3];
    const float* b           = (const float*)d_in[4];
    const float* mask        = (const float*)d_in[5];
    float* out = (float*)d_out;

    const size_t ND = (size_t)N_NODES * D;
    const int NP = 50004;                         // padded N+1, keeps 16B alignment
    float* ln        = (float*)d_ws;              // ND f32
    float* h         = ln + ND;                   // ND f32
    int*   row_start = (int*)(h + ND);            // NP ints
    int*   cursor    = row_start + NP;            // NP ints
    int*   counts    = cursor + NP;               // NP ints
    int2*  sw        = (int2*)(counts + NP);      // E int2 (8B-aligned: offset mult of 8)
    int*   partial   = (int*)(sw + E_EDGES);      // NB ints

    ln_kernel<<<N_NODES / 4, 256, 0, stream>>>(node_inputs, ln);
    gemm_kernel<<<(N_NODES + 31) / 32, 256, 0, stream>>>(ln, W, h);
    zero_counts<<<NB, 256, 0, stream>>>(counts);
    hist_kernel<<<(E_EDGES + 255) / 256, 256, 0, stream>>>(edge_index, counts);
    blocksum_kernel<<<NB, 256, 0, stream>>>(counts, partial);
    scanpartial_kernel<<<1, 256, 0, stream>>>(partial);
    writeoffs_kernel<<<NB, 256, 0, stream>>>(counts, partial, row_start, cursor);
    reorder_kernel<<<(E_EDGES + 255) / 256, 256, 0, stream>>>(edge_index, edge_w,
                                                              cursor, sw);
    gather_kernel<<<N_NODES / 8, 256, 0, stream>>>(row_start, sw, h,
                                                   b, mask, ln, out);
}

// Round 5
// 252.112 us; speedup vs baseline: 1.8925x; 1.1526x over previous
//
#include <hip/hip_runtime.h>

#define N_NODES 50000
#define D 128
#define E_EDGES 800000
#define EPS 1e-5f
#define NB 196   // ceil(N_NODES/256)

typedef __attribute__((ext_vector_type(8))) short bf16x8;
typedef __attribute__((ext_vector_type(4))) float f32x4;

static __device__ __forceinline__ unsigned short f2bf(float f) {
    unsigned u = __float_as_uint(f);
    u = (u + 0x7fffu + ((u >> 16) & 1u)) >> 16;   // RNE
    return (unsigned short)u;
}
static __device__ __forceinline__ float bf2f(unsigned short h) {
    return __uint_as_float((unsigned)h << 16);
}

// ---- Kernel 1: fused LayerNorm + H = LN @ W (bf16 MFMA), writes ln f32 + H bf16 ----
// Block: 256 thr = 4 waves, 32 rows. A-tile bf16 in swizzled LDS (8 KB).
// W fragments loaded straight from global (L2-hot) into VGPRs; no W LDS.
__global__ __launch_bounds__(256) void lngemm_kernel(const float* __restrict__ x,
                                                     const float* __restrict__ W,
                                                     float* __restrict__ ln,
                                                     unsigned short* __restrict__ Hb) {
    __shared__ __align__(16) unsigned char A_lds[32 * 256];   // 32 rows x 128 bf16, swizzled
    int tid  = threadIdx.x;
    int wv   = tid >> 6;
    int lane = tid & 63;
    int row0 = blockIdx.x * 32;

    // --- W fragments -> VGPRs: wave owns col-tiles {2wv, 2wv+1}, kb = 0..3 ---
    bf16x8 bfrag[2][4];
    {
        int colb = (lane & 15);
        int kr   = (lane >> 4) * 8;
        #pragma unroll
        for (int ci = 0; ci < 2; ++ci) {
            int col = (wv * 2 + ci) * 16 + colb;
            #pragma unroll
            for (int kb = 0; kb < 4; ++kb) {
                #pragma unroll
                for (int j = 0; j < 8; ++j) {
                    float wvf = W[(size_t)(kb * 32 + kr + j) * D + col];
                    bfrag[ci][kb][j] = (short)f2bf(wvf);
                }
            }
        }
    }

    // --- LayerNorm: wave wv handles rows row0 + wv*8 .. +7 ---
    #pragma unroll
    for (int i = 0; i < 8; ++i) {
        int lr  = wv * 8 + i;
        int row = row0 + lr;
        if (row < N_NODES) {
            float2 v = ((const float2*)(x + (size_t)row * D))[lane];
            float s = v.x + v.y;
            #pragma unroll
            for (int off = 32; off > 0; off >>= 1) s += __shfl_xor(s, off);
            float mu = s * (1.0f / D);
            float dx = v.x - mu, dy = v.y - mu;
            float vs = dx * dx + dy * dy;
            #pragma unroll
            for (int off = 32; off > 0; off >>= 1) vs += __shfl_xor(vs, off);
            float rstd = rsqrtf(vs * (1.0f / D) + EPS);
            float2 o; o.x = dx * rstd; o.y = dy * rstd;
            ((float2*)(ln + (size_t)row * D))[lane] = o;
            unsigned pk = (unsigned)f2bf(o.x) | ((unsigned)f2bf(o.y) << 16);
            // swizzled store: byte = lr*256 + (4*lane ^ ((lr&7)<<4));  lr&7 == i
            *(unsigned*)(A_lds + lr * 256 + ((4 * lane) ^ (i << 4))) = pk;
        }
    }
    __syncthreads();

    // --- MFMA: 2 row-tiles x 2 col-tiles x 4 k-blocks ---
    f32x4 acc[2][2] = {};
    #pragma unroll
    for (int kb = 0; kb < 4; ++kb) {
        #pragma unroll
        for (int rt = 0; rt < 2; ++rt) {
            int lr = rt * 16 + (lane & 15);
            bf16x8 af = *(const bf16x8*)(A_lds + lr * 256 +
                          ((kb * 64 + (lane >> 4) * 16) ^ ((lr & 7) << 4)));
            acc[rt][0] = __builtin_amdgcn_mfma_f32_16x16x32_bf16(af, bfrag[0][kb], acc[rt][0], 0, 0, 0);
            acc[rt][1] = __builtin_amdgcn_mfma_f32_16x16x32_bf16(af, bfrag[1][kb], acc[rt][1], 0, 0, 0);
        }
    }

    // --- epilogue: H bf16.  C/D layout: col = lane&15, row = (lane>>4)*4 + reg ---
    #pragma unroll
    for (int rt = 0; rt < 2; ++rt) {
        #pragma unroll
        for (int ci = 0; ci < 2; ++ci) {
            int col   = (wv * 2 + ci) * 16 + (lane & 15);
            int rbase = row0 + rt * 16 + ((lane >> 4) << 2);
            #pragma unroll
            for (int reg = 0; reg < 4; ++reg) {
                int r = rbase + reg;
                if (r < N_NODES)
                    Hb[(size_t)r * D + col] = f2bf(acc[rt][ci][reg]);
            }
        }
    }
}

// ---------------- Kernel 3: zero the degree histogram ----------------
__global__ __launch_bounds__(256) void zero_counts(int* __restrict__ counts) {
    int i = blockIdx.x * 256 + threadIdx.x;
    if (i < N_NODES) counts[i] = 0;
}

// ---------------- Kernel 4: histogram of dst ----------------
__global__ __launch_bounds__(256) void hist_kernel(const int* __restrict__ ei,
                                                   int* __restrict__ counts) {
    int e = blockIdx.x * 256 + threadIdx.x;
    if (e < E_EDGES) atomicAdd(&counts[ei[E_EDGES + e]], 1);
}

// ---------------- Kernel 5a: per-block sums of counts ----------------
__global__ __launch_bounds__(256) void blocksum_kernel(const int* __restrict__ counts,
                                                       int* __restrict__ partial) {
    __shared__ int red[256];
    int i = blockIdx.x * 256 + threadIdx.x;
    red[threadIdx.x] = (i < N_NODES) ? counts[i] : 0;
    __syncthreads();
    #pragma unroll
    for (int off = 128; off > 0; off >>= 1) {
        if (threadIdx.x < off) red[threadIdx.x] += red[threadIdx.x + off];
        __syncthreads();
    }
    if (threadIdx.x == 0) partial[blockIdx.x] = red[0];
}

// ---------------- Kernel 5b: exclusive scan of the 196 partials (1 block) --------
__global__ __launch_bounds__(256) void scanpartial_kernel(int* __restrict__ partial) {
    __shared__ int s[256];
    int t = threadIdx.x;
    s[t] = (t < NB) ? partial[t] : 0;
    __syncthreads();
    #pragma unroll
    for (int off = 1; off < 256; off <<= 1) {
        int u = (t >= off) ? s[t - off] : 0;
        __syncthreads();
        s[t] += u;
        __syncthreads();
    }
    if (t < NB) partial[t] = (t == 0) ? 0 : s[t - 1];
}

// ---------------- Kernel 5c: block-local scan + partial offset -> row_start ------
__global__ __launch_bounds__(256) void writeoffs_kernel(const int* __restrict__ counts,
                                                        const int* __restrict__ partial,
                                                        int* __restrict__ row_start,
                                                        int* __restrict__ cursor) {
    __shared__ int s[256];
    int t = threadIdx.x;
    int i = blockIdx.x * 256 + t;
    s[t] = (i < N_NODES) ? counts[i] : 0;
    __syncthreads();
    #pragma unroll
    for (int off = 1; off < 256; off <<= 1) {
        int u = (t >= off) ? s[t - off] : 0;
        __syncthreads();
        s[t] += u;
        __syncthreads();
    }
    int excl = partial[blockIdx.x] + ((t == 0) ? 0 : s[t - 1]);
    if (i < N_NODES) { row_start[i] = excl; cursor[i] = excl; }
    if (i == N_NODES - 1) row_start[N_NODES] = E_EDGES;
}

// ------- Kernel 6: reorder edges into CSR order, packed (src, w) int2 ------------
__global__ __launch_bounds__(256) void reorder_kernel(const int* __restrict__ ei,
                                                      const float* __restrict__ ew,
                                                      int* __restrict__ cursor,
                                                      int2* __restrict__ sw) {
    int e = blockIdx.x * 256 + threadIdx.x;
    if (e >= E_EDGES) return;
    int dst = ei[E_EDGES + e];
    int pos = atomicAdd(&cursor[dst], 1);
    int2 p; p.x = ei[e]; p.y = __float_as_int(ew[e]);
    sw[pos] = p;
}

// ------- Kernel 7: gather-aggregate (bf16 H) + fused bias/dropout/residual -------
// Half-wave (32 lanes) per node; lane covers 4 of D=128 (ushort4 = 8B).
__global__ __launch_bounds__(256) void gather_kernel(const int* __restrict__ row_start,
                                                     const int2* __restrict__ sw,
                                                     const unsigned short* __restrict__ Hb,
                                                     const float* __restrict__ b,
                                                     const float* __restrict__ mask,
                                                     const float* __restrict__ ln,
                                                     float* __restrict__ out) {
    int wave = threadIdx.x >> 6;
    int lane = threadIdx.x & 63;
    int half = lane >> 5;
    int l    = lane & 31;
    int node = blockIdx.x * 8 + wave * 2 + half;   // 6250 * 8 = 50000 exact
    int beg = row_start[node], end = row_start[node + 1];
    float4 acc = make_float4(0.f, 0.f, 0.f, 0.f);
    int e = beg;
    for (; e + 8 <= end; e += 8) {                 // 8-edge MLP
        int2 p[8]; ushort4 hv[8];
        #pragma unroll
        for (int j = 0; j < 8; ++j) p[j] = sw[e + j];
        #pragma unroll
        for (int j = 0; j < 8; ++j)
            hv[j] = *(const ushort4*)(Hb + (size_t)p[j].x * D + l * 4);
        #pragma unroll
        for (int j = 0; j < 8; ++j) {
            float w = __int_as_float(p[j].y);
            acc.x = fmaf(w, bf2f(hv[j].x), acc.x);
            acc.y = fmaf(w, bf2f(hv[j].y), acc.y);
            acc.z = fmaf(w, bf2f(hv[j].z), acc.z);
            acc.w = fmaf(w, bf2f(hv[j].w), acc.w);
        }
    }
    for (; e < end; ++e) {
        int2 p0 = sw[e];
        ushort4 h0 = *(const ushort4*)(Hb + (size_t)p0.x * D + l * 4);
        float w = __int_as_float(p0.y);
        acc.x = fmaf(w, bf2f(h0.x), acc.x);
        acc.y = fmaf(w, bf2f(h0.y), acc.y);
        acc.z = fmaf(w, bf2f(h0.z), acc.z);
        acc.w = fmaf(w, bf2f(h0.w), acc.w);
    }
    size_t o4 = (size_t)node * 32 + l;
    float4 bv = ((const float4*)b)[l];
    float4 mv = ((const float4*)mask)[o4];
    float4 lv = ((const float4*)ln)[o4];
    float4 r;
    r.x = (acc.x + bv.x) * mv.x - lv.x;
    r.y = (acc.y + bv.y) * mv.y - lv.y;
    r.z = (acc.z + bv.z) * mv.z - lv.z;
    r.w = (acc.w + bv.w) * mv.w - lv.w;
    ((float4*)out)[o4] = r;
}

extern "C" void kernel_launch(void* const* d_in, const int* in_sizes, int n_in,
                              void* d_out, int out_size, void* d_ws, size_t ws_size,
                              hipStream_t stream) {
    const float* node_inputs = (const float*)d_in[0];
    const int*   edge_index  = (const int*)d_in[1];
    const float* edge_w      = (const float*)d_in[2];
    const float* W           = (const float*)d_in[3];
    const float* b           = (const float*)d_in[4];
    const float* mask        = (const float*)d_in[5];
    float* out = (float*)d_out;

    const size_t ND = (size_t)N_NODES * D;
    const int NP = 50004;                             // padded N+1, even
    float*          ln        = (float*)d_ws;         // ND f32
    unsigned short* Hb        = (unsigned short*)(ln + ND);   // ND bf16
    int*            row_start = (int*)(Hb + ND);      // NP ints
    int*            cursor    = row_start + NP;       // NP ints
    int*            counts    = cursor + NP;          // NP ints
    int2*           sw        = (int2*)(counts + NP); // E int2 (8B aligned)
    int*            partial   = (int*)(sw + E_EDGES); // NB ints

    lngemm_kernel<<<(N_NODES + 31) / 32, 256, 0, stream>>>(node_inputs, W, ln, Hb);
    zero_counts<<<NB, 256, 0, stream>>>(counts);
    hist_kernel<<<(E_EDGES + 255) / 256, 256, 0, stream>>>(edge_index, counts);
    blocksum_kernel<<<NB, 256, 0, stream>>>(counts, partial);
    scanpartial_kernel<<<1, 256, 0, stream>>>(partial);
    writeoffs_kernel<<<NB, 256, 0, stream>>>(counts, partial, row_start, cursor);
    reorder_kernel<<<(E_EDGES + 255) / 256, 256, 0, stream>>>(edge_index, edge_w,
                                                              cursor, sw);
    gather_kernel<<<N_NODES / 8, 256, 0, stream>>>(row_start, sw, Hb,
                                                   b, mask, ln, out);
}